// Round 1
// baseline (2022.762 us; speedup 1.0000x reference)
//
#include <hip/hip_runtime.h>
#include <hip/hip_bf16.h>

#define B_  8
#define L_  512
#define DM  512
#define NL  4
#define DS  16
#define HOR 96
#define DC  4
#define DI  1024
#define DTR 32

typedef __bf16 bf16_t;
typedef __bf16 b8_t __attribute__((ext_vector_type(8)));
typedef float  f4_t __attribute__((ext_vector_type(4)));

__device__ __forceinline__ float sigmoidf_(float x){ return 1.f/(1.f+__expf(-x)); }

// ---------- f32 -> bf16 convert (x4 vectorized) ----------
__global__ __launch_bounds__(256) void k_cvt(const float* __restrict__ in, bf16_t* __restrict__ out, int n4){
  int i = blockIdx.x*256 + threadIdx.x;
  if (i >= n4) return;
  f4_t v = ((const f4_t*)in)[i];
  bf16_t* o = out + (size_t)i*4;
  o[0]=(bf16_t)v[0]; o[1]=(bf16_t)v[1]; o[2]=(bf16_t)v[2]; o[3]=(bf16_t)v[3];
}

// ---------- embed: h[b,l,d] = x[b,l]*ew[d] + eb[d] ----------
__global__ __launch_bounds__(256) void k_embed(const float* __restrict__ x, const float* __restrict__ ew,
                                               const float* __restrict__ eb, float* __restrict__ h){
  int idx = blockIdx.x*256 + threadIdx.x;   // B*L*DM
  int d = idx & (DM-1); int t = idx >> 9;
  h[idx] = x[t]*ew[d] + eb[d];
}

// ---------- rmsnorm (fp32 in, bf16 out) ----------
__global__ __launch_bounds__(256) void k_rms(const float* __restrict__ h, const float* __restrict__ w,
                                             bf16_t* __restrict__ o){
  int t = blockIdx.x; int tid = threadIdx.x;
  const float* hp = h + (size_t)t*DM;
  float v0 = hp[tid], v1 = hp[tid+256];
  float s = v0*v0 + v1*v1;
  #pragma unroll
  for (int m=32;m;m>>=1) s += __shfl_xor(s, m);
  __shared__ float red[4];
  if ((tid&63)==0) red[tid>>6]=s;
  __syncthreads();
  float tot = red[0]+red[1]+red[2]+red[3];
  float sc = rsqrtf(tot*(1.f/DM) + 1e-5f);
  o[(size_t)t*DM + tid]       = (bf16_t)(v0*sc*w[tid]);
  o[(size_t)t*DM + tid + 256] = (bf16_t)(v1*sc*w[tid+256]);
}

// ---------- bf16 MFMA GEMM: C[M,N] = A[M,K] @ W[N,K]^T ----------
// MODE 0: C=acc | MODE 1: C=acc + bf16 copy | MODE 2: C=softplus(acc+bias[n]) | MODE 3: C=resid+acc
#define TM 64
#define TN 64
#define TK 32
#define LDS_S 40   // padded row stride (bf16 elems): 80B, keeps 16B align, <=2-way bank alias

template<int MODE>
__global__ __launch_bounds__(256) void k_gemm(const bf16_t* __restrict__ A, int lda,
                                              const bf16_t* __restrict__ W, int ldw,
                                              float* __restrict__ C, int ldc, int K,
                                              const float* __restrict__ bias,
                                              bf16_t* __restrict__ Cbf,
                                              const float* __restrict__ resid){
  __shared__ bf16_t As[TM*LDS_S];
  __shared__ bf16_t Ws[TN*LDS_S];
  int tid = threadIdx.x;
  int m0 = blockIdx.y*TM, n0 = blockIdx.x*TN;
  int wave = tid>>6, lane = tid&63;
  int wm = (wave>>1)<<5, wn = (wave&1)<<5;
  int lr = lane&15, q = lane>>4;
  int srow = tid>>2, sch = (tid&3)<<3;
  const bf16_t* Ag = A + (size_t)(m0+srow)*lda + sch;
  const bf16_t* Wg = W + (size_t)(n0+srow)*ldw + sch;
  f4_t acc[2][2] = {};
  for (int k0=0;k0<K;k0+=TK){
    b8_t av = *(const b8_t*)(Ag + k0);
    b8_t wv = *(const b8_t*)(Wg + k0);
    *(b8_t*)(As + srow*LDS_S + sch) = av;
    *(b8_t*)(Ws + srow*LDS_S + sch) = wv;
    __syncthreads();
    b8_t a0 = *(const b8_t*)(As + (wm+lr)*LDS_S + (q<<3));
    b8_t a1 = *(const b8_t*)(As + (wm+16+lr)*LDS_S + (q<<3));
    b8_t b0 = *(const b8_t*)(Ws + (wn+lr)*LDS_S + (q<<3));
    b8_t b1 = *(const b8_t*)(Ws + (wn+16+lr)*LDS_S + (q<<3));
    acc[0][0] = __builtin_amdgcn_mfma_f32_16x16x32_bf16(a0,b0,acc[0][0],0,0,0);
    acc[0][1] = __builtin_amdgcn_mfma_f32_16x16x32_bf16(a0,b1,acc[0][1],0,0,0);
    acc[1][0] = __builtin_amdgcn_mfma_f32_16x16x32_bf16(a1,b0,acc[1][0],0,0,0);
    acc[1][1] = __builtin_amdgcn_mfma_f32_16x16x32_bf16(a1,b1,acc[1][1],0,0,0);
    __syncthreads();
  }
  #pragma unroll
  for (int i=0;i<2;i++)
  #pragma unroll
  for (int j=0;j<2;j++){
    int col = n0 + wn + (j<<4) + lr;
    int rb  = m0 + wm + (i<<4) + (q<<2);
    #pragma unroll
    for (int r=0;r<4;r++){
      size_t off = (size_t)(rb+r)*ldc + col;
      float v = acc[i][j][r];
      if (MODE==2){ float xv = v + bias[col]; v = (xv>20.f)?xv:log1pf(__expf(xv)); C[off]=v; }
      else if (MODE==3){ C[off] = resid[off] + v; }
      else { C[off] = v; if (MODE==1) Cbf[off] = (bf16_t)v; }
    }
  }
}

// ---------- causal depthwise conv (k=4) + bias + silu ----------
__global__ __launch_bounds__(256) void k_conv(const float* __restrict__ xz, const float* __restrict__ cw,
                                              const float* __restrict__ cb, float* __restrict__ xin,
                                              bf16_t* __restrict__ xinbf){
  int idx = blockIdx.x*256 + threadIdx.x;   // B*L*DI
  int c = idx & (DI-1); int t = idx >> 10; int l = t & (L_-1);
  float acc = cb[c];
  const float* wr = cw + c*DC;
  #pragma unroll
  for (int k=0;k<DC;k++){
    int ll = l + k - (DC-1);
    if (ll >= 0) acc += xz[(size_t)(t + k - (DC-1))*(2*DI) + c] * wr[k];
  }
  float s = acc * sigmoidf_(acc);
  xin[idx] = s;
  xinbf[idx] = (bf16_t)s;
}

// ---------- selective scan: 16 lanes per (b,ch) chain, lane = state n ----------
__global__ __launch_bounds__(256) void k_scan(const float* __restrict__ xz, const float* __restrict__ xin,
                                              const float* __restrict__ dbc, const float* __restrict__ Alog,
                                              const float* __restrict__ Dp, bf16_t* __restrict__ ybf){
  int tid = threadIdx.x;
  int chain = (blockIdx.x<<4) + (tid>>4);
  int n = tid & 15;
  int b = chain >> 10, ch = chain & (DI-1);
  float An = -__expf(Alog[ch*DS + n]);
  float Dv = Dp[ch];
  float hst = 0.f;
  int tbase = b << 9;
  for (int l=0;l<L_;l++){
    int t = tbase + l;
    float de = xz[(size_t)t*(2*DI) + ch];          // delta (aliased into xin-half)
    float zv = xz[(size_t)t*(2*DI) + DI + ch];     // z
    float xv = xin[(size_t)t*DI + ch];
    float Bn = dbc[t*64 + DTR + n];
    float Cn = dbc[t*64 + DTR + DS + n];
    float dA = __expf(de * An);
    hst = dA*hst + (de*Bn)*xv;
    float con = hst * Cn;
    con += __shfl_xor(con, 8, 16);
    con += __shfl_xor(con, 4, 16);
    con += __shfl_xor(con, 2, 16);
    con += __shfl_xor(con, 1, 16);
    if (n==0){
      float y = con + Dv*xv;
      y *= zv * sigmoidf_(zv);
      ybf[(size_t)t*DI + ch] = (bf16_t)y;
    }
  }
}

// ---------- head: out[b,hh] = h[b,L-1,:] . head_w[hh,:] + head_b[hh] ----------
__global__ __launch_bounds__(256) void k_head(const float* __restrict__ h, const float* __restrict__ hw,
                                              const float* __restrict__ hb, float* __restrict__ out){
  int wave = threadIdx.x>>6, lane = threadIdx.x&63;
  int gw = blockIdx.x*4 + wave;                    // < B_*HOR
  int b = gw / HOR, hh = gw % HOR;
  const float* hp = h + ((size_t)b*L_ + (L_-1))*DM;
  const float* wp = hw + (size_t)hh*DM;
  float s = 0.f;
  #pragma unroll
  for (int k=0;k<DM;k+=64) s += hp[k+lane]*wp[k+lane];
  #pragma unroll
  for (int m=32;m;m>>=1) s += __shfl_xor(s, m);
  if (lane==0) out[gw] = s + hb[hh];
}

extern "C" void kernel_launch(void* const* d_in, const int* in_sizes, int n_in,
                              void* d_out, int out_size, void* d_ws, size_t ws_size,
                              hipStream_t stream){
  const float* x    = (const float*)d_in[0];
  const float* ew   = (const float*)d_in[1];
  const float* eb   = (const float*)d_in[2];
  const float* nw   = (const float*)d_in[3];
  const float* ipw  = (const float*)d_in[4];
  const float* cw   = (const float*)d_in[5];
  const float* cb   = (const float*)d_in[6];
  const float* xpw  = (const float*)d_in[7];
  const float* dtw  = (const float*)d_in[8];
  const float* dtb  = (const float*)d_in[9];
  const float* alog = (const float*)d_in[10];
  const float* Dp   = (const float*)d_in[11];
  const float* opw  = (const float*)d_in[12];
  const float* hw   = (const float*)d_in[13];
  const float* hb   = (const float*)d_in[14];
  float* out = (float*)d_out;

  char* ws = (char*)d_ws;
  float*  h     = (float*)(ws);                      //  8 MB   (B*L*DM f32)
  bf16_t* hnorm = (bf16_t*)(ws + (size_t)( 8<<20));  //  4 MB
  float*  xz    = (float*)(ws + (size_t)(12<<20));   // 32 MB   (xin-half later reused as delta)
  float*  xin   = (float*)(ws + (size_t)(44<<20));   // 16 MB
  bf16_t* xinbf = (bf16_t*)(ws + (size_t)(60<<20));  //  8 MB   (reused as y-bf16 by scan)
  float*  dbc   = (float*)(ws + (size_t)(68<<20));   //  1 MB
  bf16_t* dbcbf = (bf16_t*)(ws + (size_t)(69<<20));  // .5 MB
  bf16_t* w_in  = (bf16_t*)(ws + (size_t)(70<<20));  //  8 MB
  bf16_t* w_out = (bf16_t*)(ws + (size_t)(78<<20));  //  4 MB
  bf16_t* w_xp  = (bf16_t*)(ws + (size_t)(82<<20));  // .5 MB
  bf16_t* w_dt  = (bf16_t*)(ws + (size_t)(83<<20));  // .25 MB  (total ~83.3 MB)

  // weight dtype conversion (every launch; inputs restored by harness)
  k_cvt<<<(NL*2*DI*DM/4)/256,256,0,stream>>>(ipw, w_in, NL*2*DI*DM/4);
  k_cvt<<<(NL*64*DI/4)/256,256,0,stream>>>(xpw, w_xp, NL*64*DI/4);
  k_cvt<<<(NL*DI*DTR/4)/256,256,0,stream>>>(dtw, w_dt, NL*DI*DTR/4);
  k_cvt<<<(NL*DM*DI/4)/256,256,0,stream>>>(opw, w_out, NL*DM*DI/4);

  k_embed<<<(B_*L_*DM)/256,256,0,stream>>>(x, ew, eb, h);

  for (int i=0;i<NL;i++){
    k_rms<<<B_*L_,256,0,stream>>>(h, nw + i*DM, hnorm);
    // xz = hnorm @ in_proj^T   (M=4096,N=2048,K=512)
    k_gemm<0><<<dim3(2*DI/TN, B_*L_/TM),256,0,stream>>>(hnorm, DM, w_in + (size_t)i*2*DI*DM, DM,
                                                        xz, 2*DI, DM, nullptr, nullptr, nullptr);
    k_conv<<<(B_*L_*DI)/256,256,0,stream>>>(xz, cw + i*DI*DC, cb + i*DI, xin, xinbf);
    // dbc = xin @ x_proj^T     (M=4096,N=64,K=1024)
    k_gemm<1><<<dim3(64/TN, B_*L_/TM),256,0,stream>>>(xinbf, DI, w_xp + (size_t)i*64*DI, DI,
                                                      dbc, 64, DI, nullptr, dbcbf, nullptr);
    // delta = softplus(dbc[:, :32] @ dt_w^T + dt_b) -> stored into xin-half of xz
    k_gemm<2><<<dim3(DI/TN, B_*L_/TM),256,0,stream>>>(dbcbf, 64, w_dt + (size_t)i*DI*DTR, DTR,
                                                      xz, 2*DI, DTR, dtb + i*DI, nullptr, nullptr);
    // selective scan + D*x + silu(z) gate -> y (bf16, into xinbf)
    k_scan<<<(B_*DI)/16,256,0,stream>>>(xz, xin, dbc, alog + i*DI*DS, Dp + i*DI, xinbf);
    // h = h + y @ out_proj^T   (M=4096,N=512,K=1024)
    k_gemm<3><<<dim3(DM/TN, B_*L_/TM),256,0,stream>>>(xinbf, DI, w_out + (size_t)i*DM*DI, DI,
                                                      h, DM, DI, nullptr, nullptr, h);
  }
  k_head<<<(B_*HOR)/4,256,0,stream>>>(h, hw, hb, out);
}

// Round 2
// 747.068 us; speedup vs baseline: 2.7076x; 2.7076x over previous
//
#include <hip/hip_runtime.h>
#include <hip/hip_bf16.h>

#define B_  8
#define L_  512
#define DM  512
#define NL  4
#define DS  16
#define HOR 96
#define DC  4
#define DI  1024
#define DTR 32

#define CHUNK 32
#define NCHK (L_/CHUNK)   // 16

typedef __bf16 bf16_t;
typedef __bf16 b8_t __attribute__((ext_vector_type(8)));
typedef float  f4_t __attribute__((ext_vector_type(4)));

__device__ __forceinline__ float sigmoidf_(float x){ return 1.f/(1.f+__expf(-x)); }

// ---------- f32 -> bf16 convert (x4 vectorized) ----------
__global__ __launch_bounds__(256) void k_cvt(const float* __restrict__ in, bf16_t* __restrict__ out, int n4){
  int i = blockIdx.x*256 + threadIdx.x;
  if (i >= n4) return;
  f4_t v = ((const f4_t*)in)[i];
  bf16_t* o = out + (size_t)i*4;
  o[0]=(bf16_t)v[0]; o[1]=(bf16_t)v[1]; o[2]=(bf16_t)v[2]; o[3]=(bf16_t)v[3];
}

// ---------- embed ----------
__global__ __launch_bounds__(256) void k_embed(const float* __restrict__ x, const float* __restrict__ ew,
                                               const float* __restrict__ eb, float* __restrict__ h){
  int idx = blockIdx.x*256 + threadIdx.x;   // B*L*DM
  int d = idx & (DM-1); int t = idx >> 9;
  h[idx] = x[t]*ew[d] + eb[d];
}

// ---------- rmsnorm (fp32 in, bf16 out) ----------
__global__ __launch_bounds__(256) void k_rms(const float* __restrict__ h, const float* __restrict__ w,
                                             bf16_t* __restrict__ o){
  int t = blockIdx.x; int tid = threadIdx.x;
  const float* hp = h + (size_t)t*DM;
  float v0 = hp[tid], v1 = hp[tid+256];
  float s = v0*v0 + v1*v1;
  #pragma unroll
  for (int m=32;m;m>>=1) s += __shfl_xor(s, m);
  __shared__ float red[4];
  if ((tid&63)==0) red[tid>>6]=s;
  __syncthreads();
  float tot = red[0]+red[1]+red[2]+red[3];
  float sc = rsqrtf(tot*(1.f/DM) + 1e-5f);
  o[(size_t)t*DM + tid]       = (bf16_t)(v0*sc*w[tid]);
  o[(size_t)t*DM + tid + 256] = (bf16_t)(v1*sc*w[tid+256]);
}

// ---------- bf16 MFMA GEMM: C[M,N] = A[M,K] @ W[N,K]^T ----------
// MODE 0: C=acc | MODE 1: C=acc + bf16 copy | MODE 2: C=softplus(acc+bias[n]) | MODE 3: C=resid+acc
#define TM 64
#define TN 64
#define TK 32
#define LDS_S 40

template<int MODE>
__global__ __launch_bounds__(256) void k_gemm(const bf16_t* __restrict__ A, int lda,
                                              const bf16_t* __restrict__ W, int ldw,
                                              float* __restrict__ C, int ldc, int K,
                                              const float* __restrict__ bias,
                                              bf16_t* __restrict__ Cbf,
                                              const float* __restrict__ resid){
  __shared__ bf16_t As[TM*LDS_S];
  __shared__ bf16_t Ws[TN*LDS_S];
  int tid = threadIdx.x;
  int m0 = blockIdx.y*TM, n0 = blockIdx.x*TN;
  int wave = tid>>6, lane = tid&63;
  int wm = (wave>>1)<<5, wn = (wave&1)<<5;
  int lr = lane&15, q = lane>>4;
  int srow = tid>>2, sch = (tid&3)<<3;
  const bf16_t* Ag = A + (size_t)(m0+srow)*lda + sch;
  const bf16_t* Wg = W + (size_t)(n0+srow)*ldw + sch;
  f4_t acc[2][2] = {};
  for (int k0=0;k0<K;k0+=TK){
    b8_t av = *(const b8_t*)(Ag + k0);
    b8_t wv = *(const b8_t*)(Wg + k0);
    *(b8_t*)(As + srow*LDS_S + sch) = av;
    *(b8_t*)(Ws + srow*LDS_S + sch) = wv;
    __syncthreads();
    b8_t a0 = *(const b8_t*)(As + (wm+lr)*LDS_S + (q<<3));
    b8_t a1 = *(const b8_t*)(As + (wm+16+lr)*LDS_S + (q<<3));
    b8_t b0 = *(const b8_t*)(Ws + (wn+lr)*LDS_S + (q<<3));
    b8_t b1 = *(const b8_t*)(Ws + (wn+16+lr)*LDS_S + (q<<3));
    acc[0][0] = __builtin_amdgcn_mfma_f32_16x16x32_bf16(a0,b0,acc[0][0],0,0,0);
    acc[0][1] = __builtin_amdgcn_mfma_f32_16x16x32_bf16(a0,b1,acc[0][1],0,0,0);
    acc[1][0] = __builtin_amdgcn_mfma_f32_16x16x32_bf16(a1,b0,acc[1][0],0,0,0);
    acc[1][1] = __builtin_amdgcn_mfma_f32_16x16x32_bf16(a1,b1,acc[1][1],0,0,0);
    __syncthreads();
  }
  #pragma unroll
  for (int i=0;i<2;i++)
  #pragma unroll
  for (int j=0;j<2;j++){
    int col = n0 + wn + (j<<4) + lr;
    int rb  = m0 + wm + (i<<4) + (q<<2);
    #pragma unroll
    for (int r=0;r<4;r++){
      size_t off = (size_t)(rb+r)*ldc + col;
      float v = acc[i][j][r];
      if (MODE==2){ float xv = v + bias[col]; v = (xv>20.f)?xv:log1pf(__expf(xv)); C[off]=v; }
      else if (MODE==3){ C[off] = resid[off] + v; }
      else { C[off] = v; if (MODE==1) Cbf[off] = (bf16_t)v; }
    }
  }
}

// ---------- causal depthwise conv (k=4) + bias + silu ----------
__global__ __launch_bounds__(256) void k_conv(const float* __restrict__ xz, const float* __restrict__ cw,
                                              const float* __restrict__ cb, float* __restrict__ xin,
                                              bf16_t* __restrict__ xinbf){
  int idx = blockIdx.x*256 + threadIdx.x;   // B*L*DI
  int c = idx & (DI-1); int t = idx >> 10; int l = t & (L_-1);
  float acc = cb[c];
  const float* wr = cw + c*DC;
  #pragma unroll
  for (int k=0;k<DC;k++){
    int ll = l + k - (DC-1);
    if (ll >= 0) acc += xz[(size_t)(t + k - (DC-1))*(2*DI) + c] * wr[k];
  }
  float s = acc * sigmoidf_(acc);
  xin[idx] = s;
  xinbf[idx] = (bf16_t)s;
}

// ---------- scan phase 1: per-chunk local scan (h_in = 0) ----------
// grid: b(8) x chunk(16) x chgrp(4) = 512 blocks, 256 thr; thread = one channel
__global__ __launch_bounds__(256) void k_scan_p1(const float* __restrict__ xz, const float* __restrict__ xin,
                                                 const float* __restrict__ dbc, const float* __restrict__ Alog,
                                                 float* __restrict__ hend, float* __restrict__ aprod){
  int tid = threadIdx.x;
  int blk = blockIdx.x;
  int chgrp = blk & 3;
  int chunk = (blk>>2) & (NCHK-1);
  int b = blk >> 6;
  int ch = (chgrp<<8) + tid;
  int t0 = (b<<9) + chunk*CHUNK;
  __shared__ float Bs[CHUNK][DS];
  for (int i=tid; i<CHUNK*DS; i+=256){
    int ll = i>>4, n = i&15;
    Bs[ll][n] = dbc[(t0+ll)*64 + DTR + n];
  }
  __syncthreads();
  float An[DS], h[DS], ap[DS];
  const f4_t* Ap = (const f4_t*)(Alog + ch*DS);
  #pragma unroll
  for (int v=0;v<4;v++){
    f4_t a4 = Ap[v];
    #pragma unroll
    for (int k=0;k<4;k++){ An[v*4+k] = -__expf(a4[k]); h[v*4+k]=0.f; ap[v*4+k]=1.f; }
  }
  const float* dep = xz  + (size_t)t0*(2*DI) + ch;
  const float* xp  = xin + (size_t)t0*DI + ch;
  #pragma unroll 4
  for (int l=0;l<CHUNK;l++){
    float de = dep[(size_t)l*(2*DI)];
    float xv = xp[(size_t)l*DI];
    float dx = de*xv;
    #pragma unroll
    for (int n=0;n<DS;n++){
      float dA = __expf(de*An[n]);
      h[n] = dA*h[n] + dx*Bs[l][n];
      ap[n] *= dA;
    }
  }
  size_t base = ((size_t)chunk*(B_*DI) + (b<<10) + ch)*DS;
  f4_t* hp  = (f4_t*)(hend + base);
  f4_t* app = (f4_t*)(aprod + base);
  #pragma unroll
  for (int v=0;v<4;v++){
    f4_t hv, av;
    #pragma unroll
    for (int k=0;k<4;k++){ hv[k]=h[v*4+k]; av[k]=ap[v*4+k]; }
    hp[v]=hv; app[v]=av;
  }
}

// ---------- scan phase 2: combine chunk transitions; hin stored into aprod ----------
__global__ __launch_bounds__(256) void k_scan_p2(const float* __restrict__ hend, float* __restrict__ ap_hin){
  int g = blockIdx.x*256 + threadIdx.x;   // B_*DI*DS = 131072 threads
  float h = 0.f;
  for (int c=0;c<NCHK;c++){
    size_t off = (size_t)c*(B_*DI*DS) + g;
    float a = ap_hin[off];
    float e = hend[off];
    ap_hin[off] = h;          // h_in for chunk c
    h = a*h + e;
  }
}

// ---------- scan phase 3: rerun with correct h_in, produce gated y (bf16) ----------
__global__ __launch_bounds__(256) void k_scan_p3(const float* __restrict__ xz, const float* __restrict__ xin,
                                                 const float* __restrict__ dbc, const float* __restrict__ Alog,
                                                 const float* __restrict__ hin, const float* __restrict__ Dp,
                                                 bf16_t* __restrict__ ybf){
  int tid = threadIdx.x;
  int blk = blockIdx.x;
  int chgrp = blk & 3;
  int chunk = (blk>>2) & (NCHK-1);
  int b = blk >> 6;
  int ch = (chgrp<<8) + tid;
  int t0 = (b<<9) + chunk*CHUNK;
  __shared__ float Bs[CHUNK][DS];
  __shared__ float Cs[CHUNK][DS];
  for (int i=tid; i<CHUNK*DS; i+=256){
    int ll = i>>4, n = i&15;
    Bs[ll][n] = dbc[(t0+ll)*64 + DTR + n];
    Cs[ll][n] = dbc[(t0+ll)*64 + DTR + DS + n];
  }
  __syncthreads();
  float An[DS], h[DS];
  const f4_t* Ap = (const f4_t*)(Alog + ch*DS);
  size_t base = ((size_t)chunk*(B_*DI) + (b<<10) + ch)*DS;
  const f4_t* hp = (const f4_t*)(hin + base);
  #pragma unroll
  for (int v=0;v<4;v++){
    f4_t a4 = Ap[v];
    f4_t hv = hp[v];
    #pragma unroll
    for (int k=0;k<4;k++){ An[v*4+k] = -__expf(a4[k]); h[v*4+k]=hv[k]; }
  }
  float Dv = Dp[ch];
  const float* dep = xz  + (size_t)t0*(2*DI) + ch;
  const float* zp  = dep + DI;
  const float* xp  = xin + (size_t)t0*DI + ch;
  bf16_t* yp = ybf + (size_t)t0*DI + ch;
  #pragma unroll 4
  for (int l=0;l<CHUNK;l++){
    float de = dep[(size_t)l*(2*DI)];
    float zv = zp[(size_t)l*(2*DI)];
    float xv = xp[(size_t)l*DI];
    float dx = de*xv;
    float y = 0.f;
    #pragma unroll
    for (int n=0;n<DS;n++){
      float dA = __expf(de*An[n]);
      h[n] = dA*h[n] + dx*Bs[l][n];
      y += h[n]*Cs[l][n];
    }
    y = (y + Dv*xv) * (zv * sigmoidf_(zv));
    yp[(size_t)l*DI] = (bf16_t)y;
  }
}

// ---------- head ----------
__global__ __launch_bounds__(256) void k_head(const float* __restrict__ h, const float* __restrict__ hw,
                                              const float* __restrict__ hb, float* __restrict__ out){
  int wave = threadIdx.x>>6, lane = threadIdx.x&63;
  int gw = blockIdx.x*4 + wave;                    // < B_*HOR
  int b = gw / HOR, hh = gw % HOR;
  const float* hp = h + ((size_t)b*L_ + (L_-1))*DM;
  const float* wp = hw + (size_t)hh*DM;
  float s = 0.f;
  #pragma unroll
  for (int k=0;k<DM;k+=64) s += hp[k+lane]*wp[k+lane];
  #pragma unroll
  for (int m=32;m;m>>=1) s += __shfl_xor(s, m);
  if (lane==0) out[gw] = s + hb[hh];
}

extern "C" void kernel_launch(void* const* d_in, const int* in_sizes, int n_in,
                              void* d_out, int out_size, void* d_ws, size_t ws_size,
                              hipStream_t stream){
  const float* x    = (const float*)d_in[0];
  const float* ew   = (const float*)d_in[1];
  const float* eb   = (const float*)d_in[2];
  const float* nw   = (const float*)d_in[3];
  const float* ipw  = (const float*)d_in[4];
  const float* cw   = (const float*)d_in[5];
  const float* cb   = (const float*)d_in[6];
  const float* xpw  = (const float*)d_in[7];
  const float* dtw  = (const float*)d_in[8];
  const float* dtb  = (const float*)d_in[9];
  const float* alog = (const float*)d_in[10];
  const float* Dp   = (const float*)d_in[11];
  const float* opw  = (const float*)d_in[12];
  const float* hw   = (const float*)d_in[13];
  const float* hb   = (const float*)d_in[14];
  float* out = (float*)d_out;

  char* ws = (char*)d_ws;
  float*  h     = (float*)(ws);                      //  8 MB
  bf16_t* hnorm = (bf16_t*)(ws + (size_t)( 8<<20));  //  4 MB
  float*  xz    = (float*)(ws + (size_t)(12<<20));   // 32 MB (xin-half reused as delta)
  float*  xin   = (float*)(ws + (size_t)(44<<20));   // 16 MB
  bf16_t* xinbf = (bf16_t*)(ws + (size_t)(60<<20));  //  8 MB (reused as y-bf16)
  float*  dbc   = (float*)(ws + (size_t)(68<<20));   //  1 MB
  bf16_t* dbcbf = (bf16_t*)(ws + (size_t)(69<<20));  // .5 MB
  bf16_t* w_in  = (bf16_t*)(ws + (size_t)(70<<20));  //  8 MB
  bf16_t* w_out = (bf16_t*)(ws + (size_t)(78<<20));  //  4 MB
  bf16_t* w_xp  = (bf16_t*)(ws + (size_t)(82<<20));  // .5 MB
  bf16_t* w_dt  = (bf16_t*)(ws + (size_t)(83<<20));  // .25 MB
  float*  hend  = (float*)(ws + (size_t)(84<<20));   //  8 MB (NCHK*B*DI*DS f32)
  float*  aphin = (float*)(ws + (size_t)(92<<20));   //  8 MB (aprod, then hin)  -> 100 MB total

  k_cvt<<<(NL*2*DI*DM/4)/256,256,0,stream>>>(ipw, w_in, NL*2*DI*DM/4);
  k_cvt<<<(NL*64*DI/4)/256,256,0,stream>>>(xpw, w_xp, NL*64*DI/4);
  k_cvt<<<(NL*DI*DTR/4)/256,256,0,stream>>>(dtw, w_dt, NL*DI*DTR/4);
  k_cvt<<<(NL*DM*DI/4)/256,256,0,stream>>>(opw, w_out, NL*DM*DI/4);

  k_embed<<<(B_*L_*DM)/256,256,0,stream>>>(x, ew, eb, h);

  for (int i=0;i<NL;i++){
    k_rms<<<B_*L_,256,0,stream>>>(h, nw + i*DM, hnorm);
    // xz = hnorm @ in_proj^T   (M=4096,N=2048,K=512)
    k_gemm<0><<<dim3(2*DI/TN, B_*L_/TM),256,0,stream>>>(hnorm, DM, w_in + (size_t)i*2*DI*DM, DM,
                                                        xz, 2*DI, DM, nullptr, nullptr, nullptr);
    k_conv<<<(B_*L_*DI)/256,256,0,stream>>>(xz, cw + i*DI*DC, cb + i*DI, xin, xinbf);
    // dbc = xin @ x_proj^T     (M=4096,N=64,K=1024)
    k_gemm<1><<<dim3(64/TN, B_*L_/TM),256,0,stream>>>(xinbf, DI, w_xp + (size_t)i*64*DI, DI,
                                                      dbc, 64, DI, nullptr, dbcbf, nullptr);
    // delta = softplus(dbc[:, :32] @ dt_w^T + dt_b) -> xin-half of xz
    k_gemm<2><<<dim3(DI/TN, B_*L_/TM),256,0,stream>>>(dbcbf, 64, w_dt + (size_t)i*DI*DTR, DTR,
                                                      xz, 2*DI, DTR, dtb + i*DI, nullptr, nullptr);
    // chunked selective scan
    k_scan_p1<<<B_*NCHK*4,256,0,stream>>>(xz, xin, dbc, alog + i*DI*DS, hend, aphin);
    k_scan_p2<<<(B_*DI*DS)/256,256,0,stream>>>(hend, aphin);
    k_scan_p3<<<B_*NCHK*4,256,0,stream>>>(xz, xin, dbc, alog + i*DI*DS, aphin, Dp + i*DI, xinbf);
    // h = h + y @ out_proj^T   (M=4096,N=512,K=1024)
    k_gemm<3><<<dim3(DM/TN, B_*L_/TM),256,0,stream>>>(xinbf, DI, w_out + (size_t)i*DM*DI, DI,
                                                      h, DM, DI, nullptr, nullptr, h);
  }
  k_head<<<(B_*HOR)/4,256,0,stream>>>(h, hw, hb, out);
}